// Round 1
// baseline (274.942 us; speedup 1.0000x reference)
//
#include <hip/hip_runtime.h>
#include <float.h>

#define BATCH 8
#define NPTS 4096
#define BLK 256
#define NCHUNK 16   // NPTS / BLK

// ---------------------------------------------------------------------------
// Kernel 1: pack each point as float4(x, y, z, x^2+y^2+z^2) for both clouds.
// Input layout is [B][3][N] (channel-major). Output: packed[cloud][b][n].
// ---------------------------------------------------------------------------
__global__ void pack_kernel(const float* __restrict__ ori,
                            const float* __restrict__ adv,
                            float4* __restrict__ packed) {
    int p = blockIdx.x * blockDim.x + threadIdx.x;      // 0 .. 2*B*N-1
    int cloud = p >> 15;                                // B*N = 32768 per cloud
    int idx = p & 32767;
    int b = idx >> 12;
    int n = idx & (NPTS - 1);
    const float* src = cloud ? adv : ori;
    float x = src[(b * 3 + 0) * NPTS + n];
    float y = src[(b * 3 + 1) * NPTS + n];
    float z = src[(b * 3 + 2) * NPTS + n];
    packed[p] = make_float4(x, y, z, x * x + y * y + z * z);
}

// ---------------------------------------------------------------------------
// Kernel 2: for each (dir, b, query-chunk) block, compute sum over the chunk's
// 256 query points of min_m dist2(q, t_m). Target cloud staged in LDS (64 KB).
// dir 0: queries = ori, targets = adv (d1).  dir 1: queries = adv, targets = ori.
// partial[bx] = sum of 256 clamped min values.
// ---------------------------------------------------------------------------
__global__ __launch_bounds__(BLK) void chamfer_main(
        const float* __restrict__ ori,
        const float* __restrict__ adv,
        const float4* __restrict__ packed,
        float* __restrict__ partial) {
    __shared__ float4 sm[NPTS];   // 64 KB

    int bx = blockIdx.x;
    int dir = bx >> 7;            // 0..1
    int b = (bx >> 4) & 7;        // 0..7
    int chunk = bx & 15;          // 0..15

    // target cloud: dir 0 -> adv (cloud 1), dir 1 -> ori (cloud 0)
    const float4* tgt = packed + (dir == 0 ? (32768 + b * NPTS) : (b * NPTS));
    for (int i = threadIdx.x; i < NPTS; i += BLK) sm[i] = tgt[i];
    __syncthreads();

    const float* qsrc = (dir == 0) ? ori : adv;
    int q = chunk * BLK + threadIdx.x;
    float qx = qsrc[(b * 3 + 0) * NPTS + q];
    float qy = qsrc[(b * 3 + 1) * NPTS + q];
    float qz = qsrc[(b * 3 + 2) * NPTS + q];
    float x2 = qx * qx + qy * qy + qz * qz;
    float ax = -2.0f * qx, ay = -2.0f * qy, az = -2.0f * qz;

    float minv = FLT_MAX;
    #pragma unroll 8
    for (int m = 0; m < NPTS; ++m) {
        float4 t = sm[m];                 // wave-uniform address -> broadcast
        float d = x2 + t.w;               // |q|^2 + |t|^2
        d = fmaf(ax, t.x, d);             // - 2 q.t
        d = fmaf(ay, t.y, d);
        d = fmaf(az, t.z, d);
        minv = fminf(minv, d);
    }
    minv = fmaxf(minv, 0.0f);             // == min over clamped distances

    // block-level sum reduction (deterministic)
    float v = minv;
    for (int off = 32; off > 0; off >>= 1) v += __shfl_down(v, off);

    __syncthreads();                      // everyone done reading sm
    float* ws = (float*)sm;               // reuse LDS for the 4 wave sums
    int wid = threadIdx.x >> 6;
    int lane = threadIdx.x & 63;
    if (lane == 0) ws[wid] = v;
    __syncthreads();
    if (threadIdx.x == 0) {
        partial[bx] = ws[0] + ws[1] + ws[2] + ws[3];
    }
}

// ---------------------------------------------------------------------------
// Kernel 3: combine the 256 partials -> scalar output. Deterministic order.
// partial layout: [dir(2)][b(8)][chunk(16)]
// ---------------------------------------------------------------------------
__global__ void finalize_kernel(const float* __restrict__ partial,
                                float* __restrict__ out) {
    __shared__ float sums[16];            // [dir*8 + b]
    int t = threadIdx.x;
    if (t < 16) {
        float s = 0.0f;
        for (int c = 0; c < NCHUNK; ++c) s += partial[t * NCHUNK + c];
        sums[t] = s;
    }
    __syncthreads();
    if (t == 0) {
        const float invN = 1.0f / (float)NPTS;
        float acc = 0.0f;
        for (int b = 0; b < BATCH; ++b) {
            float d1 = sums[b] * invN;
            float d2 = sums[8 + b] * invN;
            acc += fmaxf(d1, d2);
        }
        out[0] = acc / (float)BATCH;
    }
}

extern "C" void kernel_launch(void* const* d_in, const int* in_sizes, int n_in,
                              void* d_out, int out_size, void* d_ws, size_t ws_size,
                              hipStream_t stream) {
    const float* ori = (const float*)d_in[0];
    const float* adv = (const float*)d_in[1];
    float* out = (float*)d_out;

    // workspace layout: packed[2*B*N] float4 (1 MB), then partial[256] floats
    float4* packed = (float4*)d_ws;
    float* partial = (float*)((char*)d_ws + 2 * BATCH * NPTS * sizeof(float4));

    // 1) pack both clouds with squared norms
    pack_kernel<<<(2 * BATCH * NPTS) / BLK, BLK, 0, stream>>>(ori, adv, packed);

    // 2) main chamfer: 2 dirs * 8 batches * 16 chunks = 256 blocks
    chamfer_main<<<256, BLK, 0, stream>>>(ori, adv, packed, partial);

    // 3) finalize to scalar
    finalize_kernel<<<1, 64, 0, stream>>>(partial, out);
}

// Round 2
// 37.426 us; speedup vs baseline: 7.3462x; 7.3462x over previous
//
#include <hip/hip_runtime.h>
#include <float.h>

#define BATCH 8
#define NPTS 4096
#define BLK 256
#define Q 8            // queries per thread
#define TILE 128       // targets staged per block
#define TCH (NPTS / TILE)        // 32 target chunks
#define QCH (NPTS / (BLK * Q))   // 2 query chunks
// grid = 2 dirs * 8 batches * QCH * TCH = 1024 blocks

// ---------------------------------------------------------------------------
// Main kernel: each block handles (dir, b, query-chunk, target-chunk).
// 8 queries/thread in registers, 128-target tile in LDS (wave-uniform
// broadcast reads). Per pair: 1 add + 3 fma + ~0.5 min3 = 4.5 VALU instr.
// Partial mins combined across target-chunks via atomicMin on uint-encoded
// non-negative floats (order-independent -> deterministic).
// ---------------------------------------------------------------------------
__global__ __launch_bounds__(BLK) void chamfer_main(
        const float* __restrict__ ori,
        const float* __restrict__ adv,
        unsigned* __restrict__ mins) {
    __shared__ float4 sm[TILE];   // 2 KB

    int bx = blockIdx.x;
    int tc  = bx & (TCH - 1);          // 0..31
    int qc  = (bx >> 5) & (QCH - 1);   // 0..1
    int b   = (bx >> 6) & 7;           // 0..7
    int dir = bx >> 9;                 // 0..1

    const float* qsrc = dir ? adv : ori;   // dir0: ori->adv, dir1: adv->ori
    const float* tsrc = dir ? ori : adv;

    // stage target tile with squared norms
    int t = threadIdx.x;
    if (t < TILE) {
        int m = tc * TILE + t;
        float x = tsrc[(b * 3 + 0) * NPTS + m];
        float y = tsrc[(b * 3 + 1) * NPTS + m];
        float z = tsrc[(b * 3 + 2) * NPTS + m];
        sm[t] = make_float4(x, y, z, x * x + y * y + z * z);
    }

    // load 8 query points into registers
    float ax[Q], ay[Q], az[Q], x2[Q], mn[Q];
    #pragma unroll
    for (int i = 0; i < Q; ++i) {
        int q = qc * (BLK * Q) + i * BLK + threadIdx.x;
        float x = qsrc[(b * 3 + 0) * NPTS + q];
        float y = qsrc[(b * 3 + 1) * NPTS + q];
        float z = qsrc[(b * 3 + 2) * NPTS + q];
        ax[i] = -2.0f * x; ay[i] = -2.0f * y; az[i] = -2.0f * z;
        x2[i] = x * x + y * y + z * z;
        mn[i] = FLT_MAX;
    }
    __syncthreads();

    #pragma unroll 2
    for (int m = 0; m < TILE; m += 2) {
        float4 t0 = sm[m];
        float4 t1 = sm[m + 1];
        #pragma unroll
        for (int i = 0; i < Q; ++i) {
            float d0 = fmaf(ax[i], t0.x, x2[i] + t0.w);
            d0 = fmaf(ay[i], t0.y, d0);
            d0 = fmaf(az[i], t0.z, d0);
            float d1 = fmaf(ax[i], t1.x, x2[i] + t1.w);
            d1 = fmaf(ay[i], t1.y, d1);
            d1 = fmaf(az[i], t1.z, d1);
            mn[i] = fminf(fminf(mn[i], d0), d1);   // -> v_min3_f32
        }
    }

    // clamp >=0, encode, atomic-min across target chunks
    unsigned base = ((unsigned)(dir * 8 + b) << 12) + qc * (BLK * Q) + threadIdx.x;
    #pragma unroll
    for (int i = 0; i < Q; ++i) {
        unsigned enc = __float_as_uint(fmaxf(mn[i], 0.0f));
        atomicMin(&mins[base + i * BLK], enc);
    }
}

// ---------------------------------------------------------------------------
// Reduce: one block per (dir, b): sum 4096 query mins in a fixed order.
// ---------------------------------------------------------------------------
__global__ __launch_bounds__(BLK) void reduce_kernel(
        const unsigned* __restrict__ mins,
        float* __restrict__ bsum) {
    __shared__ float ws[4];
    const unsigned* p = mins + ((unsigned)blockIdx.x << 12);
    float s = 0.0f;
    #pragma unroll
    for (int k = 0; k < NPTS / BLK; ++k)
        s += __uint_as_float(p[k * BLK + threadIdx.x]);
    for (int off = 32; off > 0; off >>= 1) s += __shfl_down(s, off);
    int wid = threadIdx.x >> 6, lane = threadIdx.x & 63;
    if (lane == 0) ws[wid] = s;
    __syncthreads();
    if (threadIdx.x == 0)
        bsum[blockIdx.x] = ws[0] + ws[1] + ws[2] + ws[3];
}

// ---------------------------------------------------------------------------
// Finalize: scalar combine. bsum layout [dir(2)][b(8)].
// ---------------------------------------------------------------------------
__global__ void finalize_kernel(const float* __restrict__ bsum,
                                float* __restrict__ out) {
    const float invN = 1.0f / (float)NPTS;
    float acc = 0.0f;
    for (int b = 0; b < BATCH; ++b) {
        float d1 = bsum[b] * invN;
        float d2 = bsum[8 + b] * invN;
        acc += fmaxf(d1, d2);
    }
    out[0] = acc / (float)BATCH;
}

extern "C" void kernel_launch(void* const* d_in, const int* in_sizes, int n_in,
                              void* d_out, int out_size, void* d_ws, size_t ws_size,
                              hipStream_t stream) {
    const float* ori = (const float*)d_in[0];
    const float* adv = (const float*)d_in[1];
    float* out = (float*)d_out;

    // ws layout: mins[2*B*N] uints (256 KB), then bsum[16] floats
    unsigned* mins = (unsigned*)d_ws;
    float* bsum = (float*)((char*)d_ws + 2 * BATCH * NPTS * sizeof(unsigned));

    // init mins to 0xFFFFFFFF (> any encoded non-negative float)
    hipMemsetAsync(mins, 0xFF, 2 * BATCH * NPTS * sizeof(unsigned), stream);

    chamfer_main<<<2 * BATCH * QCH * TCH, BLK, 0, stream>>>(ori, adv, mins);
    reduce_kernel<<<2 * BATCH, BLK, 0, stream>>>(mins, bsum);
    finalize_kernel<<<1, 1, 0, stream>>>(bsum, out);
}

// Round 3
// 36.028 us; speedup vs baseline: 7.6314x; 1.0388x over previous
//
#include <hip/hip_runtime.h>
#include <float.h>

#define BATCH 8
#define NPTS 4096
#define BLK 256
#define Q 8                      // queries per thread
#define TILE 256                 // targets staged per block
#define TCH (NPTS / TILE)        // 16 target chunks
#define QCH (NPTS / (BLK * Q))   // 2 query chunks
// grid = 2 dirs * 8 batches * QCH * TCH = 512 blocks

// ---------------------------------------------------------------------------
// Main kernel: block = (dir, b, query-chunk, target-chunk).
// Q=8 queries/thread in registers; TILE targets in LDS as float4(x,y,z,|t|^2).
// Inner loop accumulates mn = min_m ( t.w - 2 q.t ) -- a pure 3-FMA chain per
// pair starting from t.w (|q|^2 added once at the end). 3.5 VALU instr/pair.
// Each block writes partial mins (incl. |q|^2) to partials[dirb][tc][q].
// Every slot written exactly once -> no init, no atomics, deterministic.
// ---------------------------------------------------------------------------
__global__ __launch_bounds__(BLK) void chamfer_main(
        const float* __restrict__ ori,
        const float* __restrict__ adv,
        float* __restrict__ partials) {
    __shared__ float4 sm[TILE];   // 4 KB

    int bx  = blockIdx.x;
    int tc  = bx & (TCH - 1);          // 0..15
    int qc  = (bx >> 4) & (QCH - 1);   // 0..1
    int b   = (bx >> 5) & 7;           // 0..7
    int dir = bx >> 8;                 // 0..1

    const float* qsrc = dir ? adv : ori;   // dir0: ori->adv, dir1: adv->ori
    const float* tsrc = dir ? ori : adv;

    // stage target tile with squared norms (coalesced per channel row)
    {
        int m = tc * TILE + threadIdx.x;
        float x = tsrc[(b * 3 + 0) * NPTS + m];
        float y = tsrc[(b * 3 + 1) * NPTS + m];
        float z = tsrc[(b * 3 + 2) * NPTS + m];
        sm[threadIdx.x] = make_float4(x, y, z, x * x + y * y + z * z);
    }

    // load Q query points into registers
    float ax[Q], ay[Q], az[Q], x2[Q], mn[Q];
    #pragma unroll
    for (int i = 0; i < Q; ++i) {
        int q = qc * (BLK * Q) + i * BLK + threadIdx.x;
        float x = qsrc[(b * 3 + 0) * NPTS + q];
        float y = qsrc[(b * 3 + 1) * NPTS + q];
        float z = qsrc[(b * 3 + 2) * NPTS + q];
        ax[i] = -2.0f * x; ay[i] = -2.0f * y; az[i] = -2.0f * z;
        x2[i] = x * x + y * y + z * z;
        mn[i] = FLT_MAX;
    }
    __syncthreads();

    #pragma unroll 1
    for (int m = 0; m < TILE; m += 4) {
        float4 t0 = sm[m];
        float4 t1 = sm[m + 1];
        float4 t2 = sm[m + 2];
        float4 t3 = sm[m + 3];
        #pragma unroll
        for (int i = 0; i < Q; ++i) {
            float d0 = fmaf(az[i], t0.z, fmaf(ay[i], t0.y, fmaf(ax[i], t0.x, t0.w)));
            float d1 = fmaf(az[i], t1.z, fmaf(ay[i], t1.y, fmaf(ax[i], t1.x, t1.w)));
            float d2 = fmaf(az[i], t2.z, fmaf(ay[i], t2.y, fmaf(ax[i], t2.x, t2.w)));
            float d3 = fmaf(az[i], t3.z, fmaf(ay[i], t3.y, fmaf(ax[i], t3.x, t3.w)));
            mn[i] = fminf(fminf(mn[i], d0), d1);   // -> v_min3_f32
            mn[i] = fminf(fminf(mn[i], d2), d3);
        }
    }

    // store partial mins (add |q|^2 back); layout [dirb(16)][tc(16)][q(4096)]
    int dirb = dir * 8 + b;
    float* p = partials + (((unsigned)(dirb * TCH + tc)) << 12) + qc * (BLK * Q);
    #pragma unroll
    for (int i = 0; i < Q; ++i)
        p[i * BLK + threadIdx.x] = mn[i] + x2[i];
}

// ---------------------------------------------------------------------------
// Reduce: one block per (dir,b). For each query: min over 16 target-chunk
// partials, clamp >=0, accumulate. Fixed-order tree sum -> bsum[dirb].
// ---------------------------------------------------------------------------
__global__ __launch_bounds__(BLK) void reduce_kernel(
        const float* __restrict__ partials,
        float* __restrict__ bsum) {
    __shared__ float ws[4];
    const float* p = partials + (((unsigned)blockIdx.x * TCH) << 12);
    float s = 0.0f;
    #pragma unroll
    for (int k = 0; k < NPTS / BLK; ++k) {
        int q = k * BLK + threadIdx.x;
        float mn = FLT_MAX;
        #pragma unroll
        for (int tc = 0; tc < TCH; ++tc)
            mn = fminf(mn, p[(tc << 12) + q]);
        s += fmaxf(mn, 0.0f);
    }
    for (int off = 32; off > 0; off >>= 1) s += __shfl_down(s, off);
    int wid = threadIdx.x >> 6, lane = threadIdx.x & 63;
    if (lane == 0) ws[wid] = s;
    __syncthreads();
    if (threadIdx.x == 0)
        bsum[blockIdx.x] = ws[0] + ws[1] + ws[2] + ws[3];
}

// ---------------------------------------------------------------------------
// Finalize: scalar combine. bsum layout [dir(2)][b(8)].
// ---------------------------------------------------------------------------
__global__ void finalize_kernel(const float* __restrict__ bsum,
                                float* __restrict__ out) {
    const float invN = 1.0f / (float)NPTS;
    float acc = 0.0f;
    for (int b = 0; b < BATCH; ++b) {
        float d1 = bsum[b] * invN;
        float d2 = bsum[8 + b] * invN;
        acc += fmaxf(d1, d2);
    }
    out[0] = acc / (float)BATCH;
}

extern "C" void kernel_launch(void* const* d_in, const int* in_sizes, int n_in,
                              void* d_out, int out_size, void* d_ws, size_t ws_size,
                              hipStream_t stream) {
    const float* ori = (const float*)d_in[0];
    const float* adv = (const float*)d_in[1];
    float* out = (float*)d_out;

    // ws layout: partials[16 dirb][16 tc][4096 q] floats (4 MB), then bsum[16]
    float* partials = (float*)d_ws;
    float* bsum = (float*)((char*)d_ws + 16 * TCH * NPTS * sizeof(float));

    chamfer_main<<<2 * BATCH * QCH * TCH, BLK, 0, stream>>>(ori, adv, partials);
    reduce_kernel<<<2 * BATCH, BLK, 0, stream>>>(partials, bsum);
    finalize_kernel<<<1, 1, 0, stream>>>(bsum, out);
}

// Round 4
// 33.398 us; speedup vs baseline: 8.2324x; 1.0788x over previous
//
#include <hip/hip_runtime.h>
#include <float.h>

#define BATCH 8
#define NPTS 4096
#define BLK 256
#define Q 8                      // queries per thread
#define TILE 128                 // targets staged per block
#define TCH (NPTS / TILE)        // 32 target chunks
#define QCH (NPTS / (BLK * Q))   // 2 query chunks
// grid = 2 dirs * 8 batches * QCH * TCH = 1024 blocks (4 per CU)

// ---------------------------------------------------------------------------
// Main kernel: block = (dir, b, query-chunk, target-chunk).
// Q=8 queries/thread in registers; TILE targets in LDS as float4(x,y,z,|t|^2).
// Inner loop: register double-buffer software pipeline -- issue ds_reads for
// the NEXT 4 targets, then run the 112-VALU compute on the CURRENT 4. The
// 224-cycle compute block hides the ~120-cycle LDS latency entirely.
// Per pair: 3 fma + 0.5 min3 = 3.5 VALU instr.
// Each block writes partial mins to partials[dirb][tc][q]; every slot written
// exactly once -> no init, no atomics, deterministic.
// ---------------------------------------------------------------------------
__global__ __launch_bounds__(BLK) void chamfer_main(
        const float* __restrict__ ori,
        const float* __restrict__ adv,
        float* __restrict__ partials) {
    __shared__ float4 sm[TILE];   // 2 KB

    int bx  = blockIdx.x;
    int tc  = bx & (TCH - 1);          // 0..31
    int qc  = (bx >> 5) & (QCH - 1);   // 0..1
    int b   = (bx >> 6) & 7;           // 0..7
    int dir = bx >> 9;                 // 0..1

    const float* qsrc = dir ? adv : ori;   // dir0: ori->adv, dir1: adv->ori
    const float* tsrc = dir ? ori : adv;

    // stage target tile with squared norms
    if (threadIdx.x < TILE) {
        int m = tc * TILE + threadIdx.x;
        float x = tsrc[(b * 3 + 0) * NPTS + m];
        float y = tsrc[(b * 3 + 1) * NPTS + m];
        float z = tsrc[(b * 3 + 2) * NPTS + m];
        sm[threadIdx.x] = make_float4(x, y, z, x * x + y * y + z * z);
    }

    // load Q query points into registers
    float ax[Q], ay[Q], az[Q], x2[Q], mn[Q];
    #pragma unroll
    for (int i = 0; i < Q; ++i) {
        int q = qc * (BLK * Q) + i * BLK + threadIdx.x;
        float x = qsrc[(b * 3 + 0) * NPTS + q];
        float y = qsrc[(b * 3 + 1) * NPTS + q];
        float z = qsrc[(b * 3 + 2) * NPTS + q];
        ax[i] = -2.0f * x; ay[i] = -2.0f * y; az[i] = -2.0f * z;
        x2[i] = x * x + y * y + z * z;
        mn[i] = FLT_MAX;
    }
    __syncthreads();

#define COMPUTE4(t0, t1, t2, t3)                                               \
    {                                                                          \
        _Pragma("unroll")                                                      \
        for (int i = 0; i < Q; ++i) {                                          \
            float d0 = fmaf(az[i], (t0).z,                                     \
                       fmaf(ay[i], (t0).y, fmaf(ax[i], (t0).x, (t0).w)));      \
            float d1 = fmaf(az[i], (t1).z,                                     \
                       fmaf(ay[i], (t1).y, fmaf(ax[i], (t1).x, (t1).w)));      \
            float d2 = fmaf(az[i], (t2).z,                                     \
                       fmaf(ay[i], (t2).y, fmaf(ax[i], (t2).x, (t2).w)));      \
            float d3 = fmaf(az[i], (t3).z,                                     \
                       fmaf(ay[i], (t3).y, fmaf(ax[i], (t3).x, (t3).w)));      \
            mn[i] = fminf(fminf(mn[i], d0), d1);  /* -> v_min3_f32 */          \
            mn[i] = fminf(fminf(mn[i], d2), d3);                               \
        }                                                                      \
    }

    // software-pipelined main loop: prefetch next 4 while computing current 4
    float4 c0 = sm[0], c1 = sm[1], c2 = sm[2], c3 = sm[3];
    #pragma unroll 1
    for (int m = 0; m < TILE - 4; m += 4) {
        float4 n0 = sm[m + 4], n1 = sm[m + 5], n2 = sm[m + 6], n3 = sm[m + 7];
        COMPUTE4(c0, c1, c2, c3);
        c0 = n0; c1 = n1; c2 = n2; c3 = n3;
    }
    COMPUTE4(c0, c1, c2, c3);
#undef COMPUTE4

    // store partial mins (add |q|^2 back); layout [dirb(16)][tc(32)][q(4096)]
    int dirb = dir * 8 + b;
    float* p = partials + (((unsigned)(dirb * TCH + tc)) << 12) + qc * (BLK * Q);
    #pragma unroll
    for (int i = 0; i < Q; ++i)
        p[i * BLK + threadIdx.x] = mn[i] + x2[i];
}

// ---------------------------------------------------------------------------
// Reduce: 64 blocks = (dirb, quarter). Each block: 1024 queries, min over the
// 32 target-chunk partials, clamp >=0, fixed-order sum -> bsum[dirb*4+qq].
// ---------------------------------------------------------------------------
__global__ __launch_bounds__(BLK) void reduce_kernel(
        const float* __restrict__ partials,
        float* __restrict__ bsum) {
    __shared__ float ws[4];
    int dirb = blockIdx.x >> 2;
    int qq   = blockIdx.x & 3;
    const float* p = partials + (((unsigned)dirb * TCH) << 12);
    float s = 0.0f;
    #pragma unroll
    for (int k = 0; k < 4; ++k) {
        int q = qq * 1024 + k * BLK + threadIdx.x;
        float mn = FLT_MAX;
        #pragma unroll
        for (int t = 0; t < TCH; ++t)
            mn = fminf(mn, p[(t << 12) + q]);
        s += fmaxf(mn, 0.0f);
    }
    for (int off = 32; off > 0; off >>= 1) s += __shfl_down(s, off);
    int wid = threadIdx.x >> 6, lane = threadIdx.x & 63;
    if (lane == 0) ws[wid] = s;
    __syncthreads();
    if (threadIdx.x == 0)
        bsum[blockIdx.x] = ws[0] + ws[1] + ws[2] + ws[3];
}

// ---------------------------------------------------------------------------
// Finalize: scalar combine. bsum layout [dirb(16)][quarter(4)].
// ---------------------------------------------------------------------------
__global__ void finalize_kernel(const float* __restrict__ bsum,
                                float* __restrict__ out) {
    const float invN = 1.0f / (float)NPTS;
    float acc = 0.0f;
    for (int b = 0; b < BATCH; ++b) {
        float d1 = (bsum[b * 4] + bsum[b * 4 + 1] +
                    bsum[b * 4 + 2] + bsum[b * 4 + 3]) * invN;
        float d2 = (bsum[(8 + b) * 4] + bsum[(8 + b) * 4 + 1] +
                    bsum[(8 + b) * 4 + 2] + bsum[(8 + b) * 4 + 3]) * invN;
        acc += fmaxf(d1, d2);
    }
    out[0] = acc / (float)BATCH;
}

extern "C" void kernel_launch(void* const* d_in, const int* in_sizes, int n_in,
                              void* d_out, int out_size, void* d_ws, size_t ws_size,
                              hipStream_t stream) {
    const float* ori = (const float*)d_in[0];
    const float* adv = (const float*)d_in[1];
    float* out = (float*)d_out;

    // ws layout: partials[16 dirb][32 tc][4096 q] floats (8 MB), then bsum[64]
    float* partials = (float*)d_ws;
    float* bsum = (float*)((char*)d_ws + 16 * TCH * NPTS * sizeof(float));

    chamfer_main<<<2 * BATCH * QCH * TCH, BLK, 0, stream>>>(ori, adv, partials);
    reduce_kernel<<<64, BLK, 0, stream>>>(partials, bsum);
    finalize_kernel<<<1, 1, 0, stream>>>(bsum, out);
}

// Round 5
// 32.524 us; speedup vs baseline: 8.4535x; 1.0269x over previous
//
#include <hip/hip_runtime.h>
#include <float.h>

#define BATCH 8
#define NPTS 4096
#define BLK 256
#define QCH 32                  // query chunks per (dir,b): 128 queries each
// grid = 2 * 8 * QCH = 512 blocks, 2 per CU (LDS-limited: 64 KB each)

// ---------------------------------------------------------------------------
// Fused kernel: block = (dir, b, query-chunk of 128 queries).
// Stages the FULL 4096-point target cloud in LDS as float4(x,y,z,|t|^2).
// Thread t: qslot = t&63 -> 2 queries (qslot, qslot+64); quarter = t>>6 ->
// 1024 targets. Inner loop: ping-pong register pipeline, 8 targets/step,
// 2 queries -> 56 VALU instr between a group's ds_reads and its use.
// Per pair: 3 fma + 0.5 min3 = 3.5 VALU instr.
// Block epilogue: 4-way quarter-min via LDS, clamp, one-wave sum ->
// bsum[block]. No cross-block reduction, no atomics, deterministic.
// ---------------------------------------------------------------------------
__global__ __launch_bounds__(BLK) void chamfer_fused(
        const float* __restrict__ ori,
        const float* __restrict__ adv,
        float* __restrict__ bsum) {
    __shared__ float4 sm[NPTS];   // 64 KB

    int bx  = blockIdx.x;
    int qc  = bx & (QCH - 1);          // 0..31
    int b   = (bx >> 5) & 7;           // 0..7
    int dir = bx >> 8;                 // 0..1

    const float* qsrc = dir ? adv : ori;   // dir0: ori->adv, dir1: adv->ori
    const float* tsrc = dir ? ori : adv;

    // stage full target cloud with squared norms (coalesced per channel row)
    {
        const float* tx = tsrc + (b * 3 + 0) * NPTS;
        const float* ty = tsrc + (b * 3 + 1) * NPTS;
        const float* tz = tsrc + (b * 3 + 2) * NPTS;
        #pragma unroll
        for (int i = 0; i < NPTS / BLK; ++i) {
            int m = threadIdx.x + (i << 8);
            float x = tx[m], y = ty[m], z = tz[m];
            sm[m] = make_float4(x, y, z, fmaf(x, x, fmaf(y, y, z * z)));
        }
    }

    // two queries per thread
    int qslot = threadIdx.x & 63;
    int quarter = threadIdx.x >> 6;
    float ax0, ay0, az0, x20, mn0 = FLT_MAX;
    float ax1, ay1, az1, x21, mn1 = FLT_MAX;
    {
        const float* qx = qsrc + (b * 3 + 0) * NPTS;
        const float* qy = qsrc + (b * 3 + 1) * NPTS;
        const float* qz = qsrc + (b * 3 + 2) * NPTS;
        int q0 = qc * 128 + qslot;
        int q1 = q0 + 64;
        float x = qx[q0], y = qy[q0], z = qz[q0];
        ax0 = -2.0f * x; ay0 = -2.0f * y; az0 = -2.0f * z;
        x20 = fmaf(x, x, fmaf(y, y, z * z));
        x = qx[q1]; y = qy[q1]; z = qz[q1];
        ax1 = -2.0f * x; ay1 = -2.0f * y; az1 = -2.0f * z;
        x21 = fmaf(x, x, fmaf(y, y, z * z));
    }
    __syncthreads();

#define COMPUTE4(t0, t1, t2, t3)                                               \
    {                                                                          \
        float d00 = fmaf(az0, (t0).z,                                          \
                    fmaf(ay0, (t0).y, fmaf(ax0, (t0).x, (t0).w)));             \
        float d01 = fmaf(az0, (t1).z,                                          \
                    fmaf(ay0, (t1).y, fmaf(ax0, (t1).x, (t1).w)));             \
        float d02 = fmaf(az0, (t2).z,                                          \
                    fmaf(ay0, (t2).y, fmaf(ax0, (t2).x, (t2).w)));             \
        float d03 = fmaf(az0, (t3).z,                                          \
                    fmaf(ay0, (t3).y, fmaf(ax0, (t3).x, (t3).w)));             \
        mn0 = fminf(fminf(mn0, d00), d01);  /* -> v_min3_f32 */                \
        mn0 = fminf(fminf(mn0, d02), d03);                                     \
        float d10 = fmaf(az1, (t0).z,                                          \
                    fmaf(ay1, (t0).y, fmaf(ax1, (t0).x, (t0).w)));             \
        float d11 = fmaf(az1, (t1).z,                                          \
                    fmaf(ay1, (t1).y, fmaf(ax1, (t1).x, (t1).w)));             \
        float d12 = fmaf(az1, (t2).z,                                          \
                    fmaf(ay1, (t2).y, fmaf(ax1, (t2).x, (t2).w)));             \
        float d13 = fmaf(az1, (t3).z,                                          \
                    fmaf(ay1, (t3).y, fmaf(ax1, (t3).x, (t3).w)));             \
        mn1 = fminf(fminf(mn1, d10), d11);                                     \
        mn1 = fminf(fminf(mn1, d12), d13);                                     \
    }

    // ping-pong pipelined loop over this thread's 1024 targets
    {
        const float4* tp = sm + (quarter << 10);   // wave-uniform -> broadcast
        float4 a0 = tp[0], a1 = tp[1], a2 = tp[2], a3 = tp[3];
        float4 b0 = tp[4], b1 = tp[5], b2 = tp[6], b3 = tp[7];
        #pragma unroll 1
        for (int m = 8; m < 1024; m += 8) {
            COMPUTE4(a0, a1, a2, a3);
            a0 = tp[m];     a1 = tp[m + 1]; a2 = tp[m + 2]; a3 = tp[m + 3];
            COMPUTE4(b0, b1, b2, b3);
            b0 = tp[m + 4]; b1 = tp[m + 5]; b2 = tp[m + 6]; b3 = tp[m + 7];
        }
        COMPUTE4(a0, a1, a2, a3);
        COMPUTE4(b0, b1, b2, b3);
    }
#undef COMPUTE4

    // combine quarter-mins, clamp, and block-sum
    __syncthreads();                       // all done reading targets
    float* red = (float*)sm;
    red[threadIdx.x] = mn0;
    red[256 + threadIdx.x] = mn1;
    __syncthreads();
    if (threadIdx.x < 64) {
        int t = threadIdx.x;
        float m0 = fminf(fminf(red[t],       red[t + 64]),
                         fminf(red[t + 128], red[t + 192]));
        float m1 = fminf(fminf(red[256 + t],       red[256 + t + 64]),
                         fminf(red[256 + t + 128], red[256 + t + 192]));
        float tot = fmaxf(m0 + x20, 0.0f) + fmaxf(m1 + x21, 0.0f);
        for (int off = 32; off > 0; off >>= 1) tot += __shfl_down(tot, off);
        if (t == 0) bsum[bx] = tot;
    }
}

// ---------------------------------------------------------------------------
// Finalize: bsum layout [dir(2)][b(8)][qc(32)] -> scalar. Fixed order.
// ---------------------------------------------------------------------------
__global__ void finalize_kernel(const float* __restrict__ bsum,
                                float* __restrict__ out) {
    __shared__ float sums[16];
    int t = threadIdx.x;   // 64 threads
    if (t < 16) {
        const float* p = bsum + t * QCH;
        float s = 0.0f;
        #pragma unroll
        for (int c = 0; c < QCH; ++c) s += p[c];
        sums[t] = s;
    }
    __syncthreads();
    if (t == 0) {
        const float invN = 1.0f / (float)NPTS;
        float acc = 0.0f;
        for (int b = 0; b < BATCH; ++b) {
            float d1 = sums[b] * invN;
            float d2 = sums[8 + b] * invN;
            acc += fmaxf(d1, d2);
        }
        out[0] = acc / (float)BATCH;
    }
}

extern "C" void kernel_launch(void* const* d_in, const int* in_sizes, int n_in,
                              void* d_out, int out_size, void* d_ws, size_t ws_size,
                              hipStream_t stream) {
    const float* ori = (const float*)d_in[0];
    const float* adv = (const float*)d_in[1];
    float* out = (float*)d_out;

    float* bsum = (float*)d_ws;   // 512 floats

    chamfer_fused<<<2 * BATCH * QCH, BLK, 0, stream>>>(ori, adv, bsum);
    finalize_kernel<<<1, 64, 0, stream>>>(bsum, out);
}

// Round 6
// 32.100 us; speedup vs baseline: 8.5652x; 1.0132x over previous
//
#include <hip/hip_runtime.h>
#include <float.h>

#define BATCH 8
#define NPTS 4096
#define BLK 256
#define Q 16                     // queries per thread (256*16 = all 4096)
#define TILE 128                 // targets staged per block
#define TCH (NPTS / TILE)        // 32 target chunks
// main grid = 2 dirs * 8 batches * TCH = 512 blocks (2 per CU)

// ---------------------------------------------------------------------------
// Main kernel: block = (dir, b, target-chunk). All 4096 queries of (dir,b)
// live in the block: Q=16 per thread in registers. TILE targets in LDS as
// float4(x,y,z,|t|^2), read wave-uniform (broadcast). Q=16 amortizes each
// LDS read over 64 lanes * 16 queries = 1024 pairs, so LDS-issue cycles
// (~12 cy per ds_read_b128) stay ~2.3x under the VALU floor.
// Inner loop: ping-pong 4-target pipeline; 112 VALU instr between a pair's
// ds_read and its use covers the ~120-cy LDS latency.
// Per pair: 3 fma + 0.5 min3 = 3.5 VALU instr (|q|^2 folded out of the loop).
// Block writes partial mins to partials[dirb][tc][q]; every slot written
// exactly once -> no init, no atomics, deterministic.
// ---------------------------------------------------------------------------
__global__ __launch_bounds__(BLK) void chamfer_main(
        const float* __restrict__ ori,
        const float* __restrict__ adv,
        float* __restrict__ partials) {
    __shared__ float4 sm[TILE];   // 2 KB

    int bx  = blockIdx.x;
    int tc  = bx & (TCH - 1);          // 0..31
    int b   = (bx >> 5) & 7;           // 0..7
    int dir = bx >> 8;                 // 0..1

    const float* qsrc = dir ? adv : ori;   // dir0: ori->adv, dir1: adv->ori
    const float* tsrc = dir ? ori : adv;

    // stage target tile with squared norms
    if (threadIdx.x < TILE) {
        int m = tc * TILE + threadIdx.x;
        float x = tsrc[(b * 3 + 0) * NPTS + m];
        float y = tsrc[(b * 3 + 1) * NPTS + m];
        float z = tsrc[(b * 3 + 2) * NPTS + m];
        sm[threadIdx.x] = make_float4(x, y, z, fmaf(x, x, fmaf(y, y, z * z)));
    }

    // load Q=16 query points into registers (coalesced per channel row)
    float ax[Q], ay[Q], az[Q], x2[Q], mn[Q];
    {
        const float* qx = qsrc + (b * 3 + 0) * NPTS;
        const float* qy = qsrc + (b * 3 + 1) * NPTS;
        const float* qz = qsrc + (b * 3 + 2) * NPTS;
        #pragma unroll
        for (int i = 0; i < Q; ++i) {
            int q = i * BLK + threadIdx.x;
            float x = qx[q], y = qy[q], z = qz[q];
            ax[i] = -2.0f * x; ay[i] = -2.0f * y; az[i] = -2.0f * z;
            x2[i] = fmaf(x, x, fmaf(y, y, z * z));
            mn[i] = FLT_MAX;
        }
    }
    __syncthreads();

#define COMPUTE2(t0, t1)                                                       \
    {                                                                          \
        _Pragma("unroll")                                                      \
        for (int i = 0; i < Q; ++i) {                                          \
            float d0 = fmaf(az[i], (t0).z,                                     \
                       fmaf(ay[i], (t0).y, fmaf(ax[i], (t0).x, (t0).w)));      \
            float d1 = fmaf(az[i], (t1).z,                                     \
                       fmaf(ay[i], (t1).y, fmaf(ax[i], (t1).x, (t1).w)));      \
            mn[i] = fminf(fminf(mn[i], d0), d1);   /* -> v_min3_f32 */         \
        }                                                                      \
    }

    // ping-pong pipelined loop: prefetch next 2 targets behind 112 VALU instr
    {
        float4 a0 = sm[0], a1 = sm[1];
        float4 b0 = sm[2], b1 = sm[3];
        #pragma unroll 1
        for (int m = 4; m < TILE; m += 4) {
            COMPUTE2(a0, a1);
            a0 = sm[m];     a1 = sm[m + 1];
            COMPUTE2(b0, b1);
            b0 = sm[m + 2]; b1 = sm[m + 3];
        }
        COMPUTE2(a0, a1);
        COMPUTE2(b0, b1);
    }
#undef COMPUTE2

    // store partial mins (add |q|^2 back); layout [dirb(16)][tc(32)][q(4096)]
    int dirb = dir * 8 + b;
    float* p = partials + (((unsigned)(dirb * TCH + tc)) << 12);
    #pragma unroll
    for (int i = 0; i < Q; ++i)
        p[i * BLK + threadIdx.x] = mn[i] + x2[i];
}

// ---------------------------------------------------------------------------
// Reduce: 128 blocks = (dirb(16), slice(8)). Each block: 512 queries, min
// over 32 target-chunk partials, clamp >=0, fixed-order sum -> bsum[block].
// ---------------------------------------------------------------------------
__global__ __launch_bounds__(BLK) void reduce_kernel(
        const float* __restrict__ partials,
        float* __restrict__ bsum) {
    __shared__ float ws[4];
    int dirb  = blockIdx.x >> 3;
    int slice = blockIdx.x & 7;
    const float* p = partials + (((unsigned)dirb * TCH) << 12);
    float s = 0.0f;
    #pragma unroll
    for (int k = 0; k < 2; ++k) {
        int q = slice * 512 + k * BLK + threadIdx.x;
        float mn = FLT_MAX;
        #pragma unroll
        for (int t = 0; t < TCH; ++t)
            mn = fminf(mn, p[(t << 12) + q]);
        s += fmaxf(mn, 0.0f);
    }
    for (int off = 32; off > 0; off >>= 1) s += __shfl_down(s, off);
    int wid = threadIdx.x >> 6, lane = threadIdx.x & 63;
    if (lane == 0) ws[wid] = s;
    __syncthreads();
    if (threadIdx.x == 0)
        bsum[blockIdx.x] = ws[0] + ws[1] + ws[2] + ws[3];
}

// ---------------------------------------------------------------------------
// Finalize: bsum layout [dirb(16)][slice(8)] -> scalar. Fixed order.
// ---------------------------------------------------------------------------
__global__ void finalize_kernel(const float* __restrict__ bsum,
                                float* __restrict__ out) {
    __shared__ float sums[16];
    int t = threadIdx.x;   // 64 threads
    if (t < 16) {
        const float* p = bsum + t * 8;
        float s = 0.0f;
        #pragma unroll
        for (int c = 0; c < 8; ++c) s += p[c];
        sums[t] = s;
    }
    __syncthreads();
    if (t == 0) {
        const float invN = 1.0f / (float)NPTS;
        float acc = 0.0f;
        for (int b = 0; b < BATCH; ++b) {
            float d1 = sums[b] * invN;
            float d2 = sums[8 + b] * invN;
            acc += fmaxf(d1, d2);
        }
        out[0] = acc / (float)BATCH;
    }
}

extern "C" void kernel_launch(void* const* d_in, const int* in_sizes, int n_in,
                              void* d_out, int out_size, void* d_ws, size_t ws_size,
                              hipStream_t stream) {
    const float* ori = (const float*)d_in[0];
    const float* adv = (const float*)d_in[1];
    float* out = (float*)d_out;

    // ws layout: partials[16 dirb][32 tc][4096 q] floats (8 MB), then bsum[128]
    float* partials = (float*)d_ws;
    float* bsum = (float*)((char*)d_ws + 16 * TCH * NPTS * sizeof(float));

    chamfer_main<<<2 * BATCH * TCH, BLK, 0, stream>>>(ori, adv, partials);
    reduce_kernel<<<128, BLK, 0, stream>>>(partials, bsum);
    finalize_kernel<<<1, 64, 0, stream>>>(bsum, out);
}